// Round 3
// baseline (457.590 us; speedup 1.0000x reference)
//
#include <hip/hip_runtime.h>
#include <hip/hip_bf16.h>

#define BB   8
#define TT   1024
#define NCBN 2
#define DD   128
#define KK   8192
#define MM   8192          // B*T queries per codebook

constexpr int OUT_IDX_OFF  = BB * 256 * TT;                // 2097152
constexpr int OUT_LOSS_OFF = OUT_IDX_OFF + BB * NCBN * TT; // 2113536

#define THR   0.45f        // >= 2*worst-case |y_bf16 - y_f32| (bound ~0.34)
#define QCAP  768

typedef __attribute__((ext_vector_type(8))) short   short8;   // 8 bf16
typedef __attribute__((ext_vector_type(4))) float   float4v;

__device__ __forceinline__ unsigned short f2bf(float v) {
    unsigned u = __float_as_uint(v);
    return (unsigned short)((u + 0x7FFFu + ((u >> 16) & 1u)) >> 16);  // RNE
}

// ---------------------------------------------------------------------------
// Pack x -> Xbf[n][m][d] bf16 (row 256 B), x2[n][m] fp32 (ascending-d fmaf).
// ---------------------------------------------------------------------------
__global__ __launch_bounds__(256)
void pack_x_kernel(const float* __restrict__ x, unsigned short* __restrict__ xbf,
                   float* __restrict__ x2) {
    int g = blockIdx.x * 256 + threadIdx.x;   // n*8192 + m
    int n = g >> 13, m = g & (MM - 1);
    int b = m >> 10, t = m & (TT - 1);
    const float* xp = x + ((size_t)(b * 256 + n * 128)) * TT + t;
    unsigned short* orow = xbf + (size_t)g * DD;
    float s = 0.f;
    for (int d8 = 0; d8 < DD; d8 += 8) {
        unsigned short u[8];
#pragma unroll
        for (int j = 0; j < 8; ++j) {
            float v = xp[(size_t)(d8 + j) * TT];
            s = fmaf(v, v, s);
            u[j] = f2bf(v);
        }
        uint4 pk;
        pk.x = (unsigned)u[0] | ((unsigned)u[1] << 16);
        pk.y = (unsigned)u[2] | ((unsigned)u[3] << 16);
        pk.z = (unsigned)u[4] | ((unsigned)u[5] << 16);
        pk.w = (unsigned)u[6] | ((unsigned)u[7] << 16);
        *(uint4*)(orow + d8) = pk;
    }
    x2[g] = s;
}

// ---------------------------------------------------------------------------
// Pack codebooks -> Cbf bf16 + c2 fp32 (ascending fmaf).
// ---------------------------------------------------------------------------
__global__ __launch_bounds__(256)
void pack_c_kernel(const float* __restrict__ cb, unsigned short* __restrict__ cbf,
                   float* __restrict__ c2) {
    int g = blockIdx.x * 256 + threadIdx.x;   // n*K + k
    const float4* crow = (const float4*)(cb + (size_t)g * DD);
    unsigned short* orow = cbf + (size_t)g * DD;
    float s = 0.f;
#pragma unroll 4
    for (int i2 = 0; i2 < 16; ++i2) {
        float4 v0 = crow[2 * i2];
        float4 v1 = crow[2 * i2 + 1];
        s = fmaf(v0.x, v0.x, s); s = fmaf(v0.y, v0.y, s);
        s = fmaf(v0.z, v0.z, s); s = fmaf(v0.w, v0.w, s);
        s = fmaf(v1.x, v1.x, s); s = fmaf(v1.y, v1.y, s);
        s = fmaf(v1.z, v1.z, s); s = fmaf(v1.w, v1.w, s);
        uint4 pk;
        pk.x = (unsigned)f2bf(v0.x) | ((unsigned)f2bf(v0.y) << 16);
        pk.y = (unsigned)f2bf(v0.z) | ((unsigned)f2bf(v0.w) << 16);
        pk.z = (unsigned)f2bf(v1.x) | ((unsigned)f2bf(v1.y) << 16);
        pk.w = (unsigned)f2bf(v1.z) | ((unsigned)f2bf(v1.w) << 16);
        *(uint4*)(orow + i2 * 8) = pk;
    }
    c2[g] = s;
}

// ---------------------------------------------------------------------------
// Exact fp32 rescore: identical association to the R1 passing kernel.
// atomicMin on packed (s_bits<<32 | k) = "min s, then lowest k" (s > 0 here).
// ---------------------------------------------------------------------------
__device__ void rescore_one(int n, int m, int k,
                            const float* __restrict__ x, const float* __restrict__ cb,
                            const float* __restrict__ x2, const float* __restrict__ c2,
                            unsigned long long* __restrict__ pmin) {
    int b = m >> 10, t = m & (TT - 1);
    const float* xp = x + ((size_t)(b * 256 + n * 128)) * TT + t;
    const float* cp = cb + ((size_t)(n * KK + k)) * DD;
    float xc = 0.f;
    for (int d = 0; d < DD; ++d)
        xc = fmaf(xp[(size_t)d * TT], cp[d], xc);
    float u = x2[n * MM + m] - 2.0f * xc;
    float s = u + c2[n * KK + k];
    unsigned long long pk = ((unsigned long long)__float_as_uint(s) << 32) | (unsigned)k;
    atomicMin(pmin + (size_t)n * MM + m, pk);
}

// ---------------------------------------------------------------------------
// Screening: grid (64 q-tiles, 2 codebooks, 4 K-splits) = 512 blocks, 512 thr.
// LDS layout (both Qsh and Ash): row-major 256 B rows, 16B segs XOR-swizzled:
//   phys = row*128 + ((seg ^ (row&15))*8) shorts.  All tile bases are
//   multiples of 16, so row&15 == l15 for fragment reads -> conflict-free.
// Waves: cw = wave&3 (32 codes, ntc=2 tiles), qw = wave>>2 (64 queries,
// ntq=4 tiles register-resident). Per chunk/wave: 8 ds_read_b128, 32 MFMA.
// ---------------------------------------------------------------------------
__global__ __launch_bounds__(512, 4)
void screen_kernel(const unsigned short* __restrict__ xbf,
                   const unsigned short* __restrict__ cbf,
                   const float* __restrict__ c2,
                   const float* __restrict__ x,
                   const float* __restrict__ cb32,
                   const float* __restrict__ x2,
                   unsigned long long* __restrict__ pmin) {
    __shared__ __align__(16) unsigned short Qsh[128 * 128];   // 32 KB
    __shared__ __align__(16) unsigned short Ash[128 * 128];   // 32 KB
    __shared__ unsigned int   minU[128];
    __shared__ float          c2s[128];
    __shared__ unsigned int   qcnt;
    __shared__ unsigned int   queue[QCAP];

    const int tid = threadIdx.x;
    const int qt  = blockIdx.x;        // 0..63
    const int n   = blockIdx.y;        // 0..1
    const int ks  = blockIdx.z;        // 0..3
    const int m0  = qt * 128;
    const int k0  = ks * 2048;

    const int wave = tid >> 6, lane = tid & 63;
    const int cw = wave & 3, qw = wave >> 2;
    const int quad = lane >> 4, l15 = lane & 15;

    // per-thread staging map: unit i -> row=i>>4, logical seg=(i&15)^(row&15)
    int srow[4], soff[4];   // soff = global offset in shorts; LDS dst = i*8
#pragma unroll
    for (int p = 0; p < 4; ++p) {
        int i = tid + p * 512;
        int row = i >> 4;
        int seg = (i & 15) ^ (row & 15);
        srow[p] = i;                       // phys unit
        soff[p] = row * DD + seg * 8;      // source offset (shorts)
    }

    // ---- stage queries (once)
    {
        const unsigned short* src = xbf + ((size_t)n * MM + m0) * DD;
#pragma unroll
        for (int p = 0; p < 4; ++p) {
            uint4 v = *(const uint4*)(src + soff[p]);
            *(uint4*)(&Qsh[srow[p] * 8]) = v;
        }
    }
    if (tid < 128) minU[tid] = 0xFFFFFFFFu;
    if (tid == 0)  qcnt = 0;
    __syncthreads();

    // ---- preload query B-fragments (whole D=128) into registers
    short8 bfr[4][4];                      // [tq][k4]
#pragma unroll
    for (int tq = 0; tq < 4; ++tq) {
        int q = qw * 64 + tq * 16 + l15;   // q&15 == l15
#pragma unroll
        for (int k4 = 0; k4 < 4; ++k4) {
            int seg = k4 * 4 + quad;
            bfr[tq][k4] = *(const short8*)(&Qsh[q * 128 + ((seg ^ l15) * 8)]);
        }
    }

    float mloc[4] = {3.4e38f, 3.4e38f, 3.4e38f, 3.4e38f};
    float thr[4]  = {3.4e38f, 3.4e38f, 3.4e38f, 3.4e38f};

    const unsigned short* asrc0 = cbf + ((size_t)n * KK + k0) * DD;

#pragma unroll
    for (int phase = 0; phase < 2; ++phase) {
        for (int ch = 0; ch < 16; ++ch) {
            __syncthreads();
            {   // stage code chunk: coalesced global, swizzled LDS write
                const unsigned short* src = asrc0 + (size_t)ch * 128 * DD;
#pragma unroll
                for (int p = 0; p < 4; ++p) {
                    uint4 v = *(const uint4*)(src + soff[p]);
                    *(uint4*)(&Ash[srow[p] * 8]) = v;
                }
                if (tid < 32)
                    *(float4*)&c2s[tid * 4] =
                        *(const float4*)(c2 + (size_t)n * KK + k0 + ch * 128 + tid * 4);
            }
            __syncthreads();

            float4v acc[2][4];
#pragma unroll
            for (int tc = 0; tc < 2; ++tc)
#pragma unroll
                for (int tq = 0; tq < 4; ++tq)
                    acc[tc][tq] = (float4v){0.f, 0.f, 0.f, 0.f};

#pragma unroll
            for (int k4 = 0; k4 < 4; ++k4) {
#pragma unroll
                for (int tc = 0; tc < 2; ++tc) {
                    int r = cw * 32 + tc * 16 + l15;       // r&15 == l15
                    int seg = k4 * 4 + quad;
                    short8 a = *(const short8*)(&Ash[r * 128 + ((seg ^ l15) * 8)]);
#pragma unroll
                    for (int tq = 0; tq < 4; ++tq)
                        acc[tc][tq] = __builtin_amdgcn_mfma_f32_16x16x32_bf16(
                            a, bfr[tq][k4], acc[tc][tq], 0, 0, 0);
                }
            }

            // epilogue: y = c2 - 2*xc  (x2 is query-constant, argmin-invariant)
#pragma unroll
            for (int tc = 0; tc < 2; ++tc) {
                float4v c2r = *(const float4v*)(&c2s[cw * 32 + tc * 16 + quad * 4]);
#pragma unroll
                for (int tq = 0; tq < 4; ++tq) {
#pragma unroll
                    for (int rg = 0; rg < 4; ++rg) {
                        float y = fmaf(-2.0f, acc[tc][tq][rg], c2r[rg]);
                        if (phase == 0) {
                            mloc[tq] = fminf(mloc[tq], y);
                        } else if (y <= thr[tq]) {
                            unsigned idx  = atomicAdd(&qcnt, 1u);
                            unsigned code = (unsigned)(ch * 128 + cw * 32 + tc * 16 + quad * 4 + rg);
                            unsigned q    = (unsigned)(qw * 64 + tq * 16 + l15);
                            if (idx < QCAP) queue[idx] = (q << 11) | code;
                            else rescore_one(n, m0 + (int)q, k0 + (int)code,
                                             x, cb32, x2, c2, pmin);
                        }
                    }
                }
            }
        }

        if (phase == 0) {
            // merge per-query mins: shuffle across quads, then LDS atomicMin
#pragma unroll
            for (int tq = 0; tq < 4; ++tq) {
                float v = mloc[tq];
                v = fminf(v, __shfl_xor(v, 16, 64));
                v = fminf(v, __shfl_xor(v, 32, 64));
                if (quad == 0) {
                    unsigned u  = __float_as_uint(v);
                    unsigned mu = (u & 0x80000000u) ? ~u : (u | 0x80000000u);
                    atomicMin(&minU[qw * 64 + tq * 16 + l15], mu);
                }
            }
            __syncthreads();
#pragma unroll
            for (int tq = 0; tq < 4; ++tq) {
                unsigned mu = minU[qw * 64 + tq * 16 + l15];
                unsigned u  = (mu & 0x80000000u) ? (mu & 0x7FFFFFFFu) : ~mu;
                thr[tq] = __uint_as_float(u) + THR;
            }
        }
    }

    __syncthreads();
    // drain candidate queue: exact fp32 rescore
    unsigned total = qcnt; if (total > QCAP) total = QCAP;
    for (unsigned i = tid; i < total; i += 512) {
        unsigned ent = queue[i];
        rescore_one(n, m0 + (int)(ent >> 11), k0 + (int)(ent & 2047u),
                    x, cb32, x2, c2, pmin);
    }
}

// ---------------------------------------------------------------------------
// Gather quantized rows + indices + commitment loss.
// ---------------------------------------------------------------------------
__global__ __launch_bounds__(256)
void gather_kernel(const float* __restrict__ x, const float* __restrict__ cb,
                   const unsigned long long* __restrict__ pmin,
                   float* __restrict__ out) {
    int g  = blockIdx.x * 256 + threadIdx.x;  // 0..16383
    int t  = g & (TT - 1);
    int nn = (g >> 10) & (NCBN - 1);
    int b  = g >> 11;

    int k = (int)(pmin[(size_t)nn * MM + b * TT + t] & 0xFFFFFFFFull);
    out[OUT_IDX_OFF + (b * NCBN + nn) * TT + t] = (float)k;

    const float* crow  = cb + ((size_t)nn * KK + k) * DD;
    const float* xbase = x   + ((size_t)(b * 256 + nn * 128)) * TT + t;
    float*       obase = out + ((size_t)(b * 256 + nn * 128)) * TT + t;

    float lsum = 0.f;
#pragma unroll 4
    for (int d = 0; d < DD; d += 4) {
        float4 q = *(const float4*)(crow + d);
        float qv[4] = {q.x, q.y, q.z, q.w};
#pragma unroll
        for (int u = 0; u < 4; ++u) {
            size_t off = (size_t)(d + u) * TT;
            float xv = xbase[off];
            obase[off] = qv[u];
            float df = xv - qv[u];
            lsum = fmaf(df, df, lsum);
        }
    }

#pragma unroll
    for (int o = 32; o > 0; o >>= 1) lsum += __shfl_down(lsum, o, 64);
    __shared__ float wsum[4];
    int lane = threadIdx.x & 63, w = threadIdx.x >> 6;
    if (lane == 0) wsum[w] = lsum;
    __syncthreads();
    if (threadIdx.x == 0) {
        float tot = wsum[0] + wsum[1] + wsum[2] + wsum[3];
        atomicAdd(out + OUT_LOSS_OFF, tot * 2.384185791015625e-7f);  // 2^-22
    }
}

// ---------------------------------------------------------------------------
extern "C" void kernel_launch(void* const* d_in, const int* in_sizes, int n_in,
                              void* d_out, int out_size, void* d_ws, size_t ws_size,
                              hipStream_t stream) {
    (void)in_sizes; (void)n_in; (void)out_size; (void)ws_size;
    const float* x  = (const float*)d_in[0];
    const float* cb = (const float*)d_in[1];
    float* out = (float*)d_out;

    char* ws = (char*)d_ws;
    unsigned short* xbf = (unsigned short*)(ws);                       // 4 MiB
    unsigned short* cbf = (unsigned short*)(ws + (4u << 20));          // 4 MiB
    float* x2 = (float*)(ws + (8u << 20));                             // 64 KiB
    float* c2 = (float*)(ws + (8u << 20) + (64u << 10));               // 64 KiB
    unsigned long long* pmin =
        (unsigned long long*)(ws + (8u << 20) + (128u << 10));         // 128 KiB

    pack_x_kernel<<<dim3(64), 256, 0, stream>>>(x, xbf, x2);
    pack_c_kernel<<<dim3(64), 256, 0, stream>>>(cb, cbf, c2);
    hipMemsetAsync(pmin, 0xFF, (size_t)NCBN * MM * 8, stream);
    hipMemsetAsync((char*)d_out + (size_t)OUT_LOSS_OFF * 4, 0, 4, stream);

    screen_kernel<<<dim3(64, 2, 4), 512, 0, stream>>>(xbf, cbf, c2, x, cb, x2, pmin);
    gather_kernel<<<dim3(64), 256, 0, stream>>>(x, cb, pmin, out);
}